// Round 1
// 6660.688 us; speedup vs baseline: 1.9037x; 1.9037x over previous
//
#include <hip/hip_runtime.h>
#include <cmath>
#include <cstdint>

typedef __bf16 bf16;
typedef __bf16 bf16x8 __attribute__((ext_vector_type(8)));
typedef float f32x4 __attribute__((ext_vector_type(4)));

static __device__ __forceinline__ float gelu_exact(float x) {
    return 0.5f * x * (1.f + erff(x * 0.70710678118654752f));
}

// ---------- fp32 -> bf16 convert of x with SAME padding rows (t=-1 and t=2000 zeroed) ----------
__global__ void cvt_xpad_kernel(const float* __restrict__ x, bf16* __restrict__ xp) {
    int idx = blockIdx.x * 256 + threadIdx.x;
    if (idx >= 8 * 2002 * 128) return;
    int c = idx & 127;
    int rest = idx >> 7;            // b*2002 + tp
    int tp = rest % 2002;
    int b = rest / 2002;
    float v = 0.f;
    if (tp >= 1 && tp <= 2000) v = x[(b * 2000 + tp - 1) * 128 + c];
    xp[idx] = (bf16)v;
}

// ---------- generic transpose+convert: in fp32 [R][C] -> out [C][Rpad], zero pad r in [R,Rpad) ----------
template <typename OT>
__global__ void transpose_cvt_kernel(const float* __restrict__ in, OT* __restrict__ out,
                                     int R, int C, int Rpad) {
    __shared__ float tile[32][33];
    int tx = threadIdx.x & 31, ty = threadIdx.x >> 5;   // 32 x 8
    int r0 = blockIdx.y * 32, c0 = blockIdx.x * 32;
    for (int i = ty; i < 32; i += 8) {
        int r = r0 + i, c = c0 + tx;
        tile[i][tx] = (r < R && c < C) ? in[(size_t)r * C + c] : 0.f;
    }
    __syncthreads();
    for (int i = ty; i < 32; i += 8) {
        int c = c0 + i, r = r0 + tx;
        if (c < C && r < Rpad) out[(size_t)c * Rpad + r] = (OT)tile[tx][i];
    }
}

// ---------- transpose + split fp32 -> (hi, lo) bf16 pair: in [R][C] -> out [C][R] ----------
__global__ void transpose_split_kernel(const float* __restrict__ in, bf16* __restrict__ hi,
                                       bf16* __restrict__ lo, int R, int C) {
    __shared__ float tile[32][33];
    int tx = threadIdx.x & 31, ty = threadIdx.x >> 5;
    int r0 = blockIdx.y * 32, c0 = blockIdx.x * 32;
    for (int i = ty; i < 32; i += 8) {
        int r = r0 + i, c = c0 + tx;
        tile[i][tx] = (r < R && c < C) ? in[(size_t)r * C + c] : 0.f;
    }
    __syncthreads();
    for (int i = ty; i < 32; i += 8) {
        int c = c0 + i, r = r0 + tx;
        if (c < C && r < R) {
            float v = tile[tx][i];
            bf16 h = (bf16)v;
            size_t o = (size_t)c * R + r;
            hi[o] = h;
            lo[o] = (bf16)(v - (float)h);
        }
    }
}

// ---------- zero h1 pad row (t=2000 per batch) + persistent-LSTM state (hbuf, flags) ----------
__global__ void zero_aux_kernel(bf16* __restrict__ h1, bf16* __restrict__ hbuf,
                                unsigned int* __restrict__ flags) {
    int idx = blockIdx.x * 256 + threadIdx.x;
    if (idx < 8 * 4096) {
        int b = idx >> 12, n = idx & 4095;
        h1[((size_t)(b * 2001 + 2000)) * 4096 + n] = (bf16)0.f;
    }
    int k = idx - 8 * 4096;
    if (k >= 0 && k < 16384) hbuf[k] = (bf16)0.f;       // [2 par][2 plane][8][512]
    if (k >= 16384 && k < 16416) flags[k - 16384] = 0u; // 32 flags
}

// ---------- unified bf16 MFMA GEMM, 128x128 tile, BK=32, 256 thr (4 waves, each 64x64) ----------
// MODE 0: conv1  M=16000(b,t)    K=384  (tap,cin)  N=4096  A=xpad[b][t+tap][c]      out: gelu -> h1 bf16 [b][t][n]
// MODE 1: conv2  M=8000 (b,t')   K=12288(tap,cin)  N=1024  A=h1[b][2t'+tap][c]      out: gelu -> h2T bf16 [b][n][t']
// MODE 2: zin    M=8192 (b,s)    K=1024 (f,pad)    N=2048  A=h2T[b][s][f]           out: +bias -> Zin fp32 [b][s][n]
template <int MODE>
__launch_bounds__(256)
__global__ void gemm_kernel(const bf16* __restrict__ A, const bf16* __restrict__ BT,
                            const float* __restrict__ bias, void* __restrict__ Cout) {
    constexpr int KTOT = (MODE == 0) ? 384 : (MODE == 1) ? 12288 : 1024;
    constexpr int MTOT = (MODE == 0) ? 16000 : (MODE == 1) ? 8000 : 8192;
    __shared__ __align__(16) bf16 As[128 * 32];
    __shared__ __align__(16) bf16 Bs[128 * 32];
    const int tid = threadIdx.x;
    const int lane = tid & 63, wave = tid >> 6;
    const int m0 = blockIdx.y * 128, n0 = blockIdx.x * 128;
    const int wm = (wave >> 1) * 64, wn = (wave & 1) * 64;

    f32x4 acc[4][4];
#pragma unroll
    for (int mi = 0; mi < 4; ++mi)
#pragma unroll
        for (int ni = 0; ni < 4; ++ni) acc[mi][ni] = (f32x4){0.f, 0.f, 0.f, 0.f};

    for (int kt = 0; kt < KTOT / 32; ++kt) {
        const int k0 = kt * 32;
        __syncthreads();
#pragma unroll
        for (int s = 0; s < 2; ++s) {
            int ch = tid + s * 256;          // 512 chunks of 16B = 8KB tile
            int row = ch >> 2;
            int ko = (ch & 3) * 8;
            int m = m0 + row;
            if (m > MTOT - 1) m = MTOT - 1;
            const bf16* ga;
            if (MODE == 0) {
                int b = m / 2000, t = m - b * 2000;
                ga = A + ((size_t)(b * 2002 + t + (k0 >> 7)) * 128 + (k0 & 127) + ko);
            } else if (MODE == 1) {
                int b = m / 1000, t = m - b * 1000;
                ga = A + ((size_t)(b * 2001 + 2 * t + (k0 >> 12)) * 4096 + (k0 & 4095) + ko);
            } else {
                ga = A + ((size_t)m * 1000 + k0 + ko);   // overruns row end by <=24 elems; B rows are zero there
            }
            *(uint4*)&As[ch * 8] = *(const uint4*)ga;
            const bf16* gb = BT + ((size_t)(n0 + row) * KTOT + k0 + ko);
            *(uint4*)&Bs[ch * 8] = *(const uint4*)gb;
        }
        __syncthreads();
        bf16x8 af[4], bfr[4];
#pragma unroll
        for (int i = 0; i < 4; ++i)
            af[i] = *(const bf16x8*)&As[(wm + i * 16 + (lane & 15)) * 32 + (lane >> 4) * 8];
#pragma unroll
        for (int i = 0; i < 4; ++i)
            bfr[i] = *(const bf16x8*)&Bs[(wn + i * 16 + (lane & 15)) * 32 + (lane >> 4) * 8];
#pragma unroll
        for (int mi = 0; mi < 4; ++mi)
#pragma unroll
            for (int ni = 0; ni < 4; ++ni)
                acc[mi][ni] = __builtin_amdgcn_mfma_f32_16x16x32_bf16(af[mi], bfr[ni], acc[mi][ni], 0, 0, 0);
    }

#pragma unroll
    for (int mi = 0; mi < 4; ++mi) {
        int rb = m0 + wm + mi * 16 + (lane >> 4) * 4;
#pragma unroll
        for (int ni = 0; ni < 4; ++ni) {
            int col = n0 + wn + ni * 16 + (lane & 15);
#pragma unroll
            for (int i = 0; i < 4; ++i) {
                int row = rb + i;
                float v = acc[mi][ni][i];
                if (MODE == 0) {
                    float y = gelu_exact(v + bias[col]);
                    int b = row / 2000, t = row - b * 2000;
                    ((bf16*)Cout)[(size_t)(b * 2001 + t) * 4096 + col] = (bf16)y;
                } else if (MODE == 1) {
                    if (row < 8000) {
                        float y = gelu_exact(v + bias[col]);
                        int b = row / 1000, t = row - b * 1000;
                        ((bf16*)Cout)[(size_t)(b * 1024 + col) * 1000 + t] = (bf16)y;
                    }
                } else {
                    ((float*)Cout)[(size_t)row * 2048 + col] = v + bias[col];
                }
            }
        }
    }
}

// ---------- persistent LSTM: all 1024 steps in ONE kernel, 32 wgs, device-scope flag barrier ----------
// wg w owns hidden units [16w, 16w+16). Wr slice (64 gate-cols x 512, split hi/lo bf16) lives in LDS
// for the whole sequence. h is exchanged via a tiny double-buffered global buffer hbuf[2][2][8][512].
// wave g computes gate g's 16x16 z-tile via MFMA (3 products: hh, lh, hl => ~fp32 accuracy).
__launch_bounds__(256)
__global__ void lstm_persist_kernel(const float* __restrict__ Zin,
                                    const bf16* __restrict__ WrHi,
                                    const bf16* __restrict__ WrLo,
                                    bf16* __restrict__ hbuf,
                                    unsigned int* __restrict__ flags,
                                    float* __restrict__ out) {
    __shared__ __align__(16) unsigned char WrS[2][65536];  // [plane][64 cols x 512 k] bf16, XOR-swizzled
    __shared__ __align__(16) unsigned char hS[2][8192];    // [plane][8 rows x 512 k] bf16, XOR-swizzled
    __shared__ float zex[2][4][128];                       // [parity][gate][b*16+u]
    const int tid = threadIdx.x;
    const int lane = tid & 63;
    const int wv = tid >> 6;          // wave == gate
    const int w = blockIdx.x;

    // one-time: load Wr slice (both planes) into LDS with ((col&7)<<4) byte-XOR swizzle
    for (int idx = tid; idx < 8192; idx += 256) {
        int p = idx >> 12, r = idx & 4095;
        int lc = r >> 6, co = r & 63;
        int gcol = (lc >> 4) * 512 + w * 16 + (lc & 15);
        const bf16* src = (p ? WrLo : WrHi) + (size_t)gcol * 512 + co * 8;
        unsigned dst = (unsigned)(lc * 1024 + ((co * 16) ^ ((lc & 7) << 4)));
        *(uint4*)&WrS[p][dst] = *(const uint4*)src;
    }

    const int b = tid >> 4, u = tid & 15, j = w * 16 + u;  // epilogue mapping (tid<128)
    float c_state = 0.f;
    float zin0 = 0.f, zin1 = 0.f, zin2 = 0.f, zin3 = 0.f;
    const float invf = powf(10000.f, -(float)(2 * (j >> 1)) * (1.f / 512.f));
    if (tid < 128) {
        const float* zp = Zin + (size_t)(b * 1024) * 2048;
        zin0 = zp[j]; zin1 = zp[512 + j]; zin2 = zp[1024 + j]; zin3 = zp[1536 + j];
    }

    const int rowsel = lane & 15;       // A row (batch), rows 8..15 duplicate rows 0..7 (ignored)
    const int kq = lane >> 4;           // k quarter
    const int lc = wv * 16 + rowsel;    // local B col
    const unsigned aswz = (unsigned)((rowsel & 7) << 4);
    const unsigned bswz = (unsigned)((lc & 7) << 4);
    const unsigned abase = (unsigned)((rowsel & 7) * 1024);
    const unsigned bbase = (unsigned)(lc * 1024);

    for (int t = 0; t < 1024; ++t) {
        const int par = t & 1;
        // stage h_{t-1} into LDS (swizzled); fresh after the acquire fence of the previous step
        {
            const bf16* hb = hbuf + (size_t)par * 8192;
            for (int idx = tid; idx < 1024; idx += 256) {
                int p = idx >> 9, r = idx & 511;
                int row = r >> 6, co = r & 63;
                unsigned dst = (unsigned)(row * 1024 + ((co * 16) ^ ((row & 7) << 4)));
                *(uint4*)&hS[p][dst] = *(const uint4*)(hb + (size_t)(p * 8 + row) * 512 + co * 8);
            }
        }
        __syncthreads();
        // z-tile for gate wv: 16 k-steps x 3 products, 3 independent acc chains
        f32x4 acc0 = {0.f, 0.f, 0.f, 0.f}, acc1 = {0.f, 0.f, 0.f, 0.f}, acc2 = {0.f, 0.f, 0.f, 0.f};
#pragma unroll
        for (int kk = 0; kk < 16; ++kk) {
            unsigned ko = (unsigned)((kk * 4 + kq) * 16);
            bf16x8 ah = *(const bf16x8*)&hS[0][abase + (ko ^ aswz)];
            bf16x8 al = *(const bf16x8*)&hS[1][abase + (ko ^ aswz)];
            bf16x8 bh = *(const bf16x8*)&WrS[0][bbase + (ko ^ bswz)];
            bf16x8 bl = *(const bf16x8*)&WrS[1][bbase + (ko ^ bswz)];
            acc0 = __builtin_amdgcn_mfma_f32_16x16x32_bf16(ah, bh, acc0, 0, 0, 0);
            acc1 = __builtin_amdgcn_mfma_f32_16x16x32_bf16(al, bh, acc1, 0, 0, 0);
            acc2 = __builtin_amdgcn_mfma_f32_16x16x32_bf16(ah, bl, acc2, 0, 0, 0);
        }
        if (kq < 2) {   // valid batch rows 0..7
#pragma unroll
            for (int i = 0; i < 4; ++i)
                zex[par][wv][(kq * 4 + i) * 16 + rowsel] = acc0[i] + acc1[i] + acc2[i];
        }
        __syncthreads();
        float hval = 0.f;
        if (tid < 128) {
            float zi = zex[par][0][tid] + zin0;
            float zf = zex[par][1][tid] + zin1;
            float zg = zex[par][2][tid] + zin2;
            float zo = zex[par][3][tid] + zin3;
            float ig = 1.f / (1.f + expf(-zi));
            float fg = 1.f / (1.f + expf(-zf));
            float og = 1.f / (1.f + expf(-zo));
            float c = fg * c_state + ig * tanhf(zg);
            c_state = c;
            hval = og * tanhf(c);
            bf16 hh = (bf16)hval;
            bf16 hl = (bf16)(hval - (float)hh);
            bf16* hn = hbuf + (size_t)(par ^ 1) * 8192;
            hn[b * 512 + j] = hh;            // hi plane
            hn[4096 + b * 512 + j] = hl;     // lo plane
        }
        __syncthreads();   // drain all h stores (syncthreads implies vmcnt(0) per thread)
        if (t < 1023 && tid == 0)
            __hip_atomic_store(&flags[w], (unsigned)(t + 1), __ATOMIC_RELEASE, __HIP_MEMORY_SCOPE_AGENT);
        // off-critical-path work overlaps other wgs' spin
        if (tid < 128) {
            float ang = (float)t * invf;
            float pe = (j & 1) ? cosf(ang) : sinf(ang);
            out[(size_t)(b * 1024 + t) * 512 + j] = hval + pe;
            if (t < 1023) {
                const float* zp = Zin + (size_t)(b * 1024 + t + 1) * 2048;
                zin0 = zp[j]; zin1 = zp[512 + j]; zin2 = zp[1024 + j]; zin3 = zp[1536 + j];
            }
        }
        if (t < 1023) {
            const unsigned tgt = (unsigned)(t + 1);
            for (;;) {
                unsigned f = __hip_atomic_load(&flags[lane & 31], __ATOMIC_RELAXED,
                                               __HIP_MEMORY_SCOPE_AGENT);
                if (__all((int)(f >= tgt))) break;
                __builtin_amdgcn_s_sleep(1);
            }
            __builtin_amdgcn_fence(__ATOMIC_ACQUIRE, "agent");
        }
    }
}

extern "C" void kernel_launch(void* const* d_in, const int* in_sizes, int n_in,
                              void* d_out, int out_size, void* d_ws, size_t ws_size,
                              hipStream_t stream) {
    const float* x  = (const float*)d_in[0];
    const float* w1 = (const float*)d_in[1];
    const float* b1 = (const float*)d_in[2];
    const float* w2 = (const float*)d_in[3];
    const float* b2 = (const float*)d_in[4];
    const float* wk = (const float*)d_in[5];
    const float* wr = (const float*)d_in[6];
    const float* lb = (const float*)d_in[7];
    float* out = (float*)d_out;

    uint8_t* ws = (uint8_t*)d_ws;
    size_t off = 0;
    auto alloc = [&](size_t bytes) {
        void* p = ws + off;
        off += (bytes + 255) & ~(size_t)255;
        return p;
    };
    bf16* xpad = (bf16*)alloc((size_t)8 * 2002 * 128 * 2);
    bf16* W1T  = (bf16*)alloc((size_t)4096 * 384 * 2);
    bf16* W2T  = (bf16*)alloc((size_t)1024 * 12288 * 2);
    bf16* WkT  = (bf16*)alloc((size_t)2048 * 1024 * 2);
    bf16* WrHi = (bf16*)alloc((size_t)2048 * 512 * 2);
    bf16* WrLo = (bf16*)alloc((size_t)2048 * 512 * 2);
    bf16* h1   = (bf16*)alloc((size_t)8 * 2001 * 4096 * 2);
    bf16* h2T  = (bf16*)alloc((size_t)8 * 1024 * 1000 * 2 + 256);  // +slack for k-tail overread
    float* Zin = (float*)alloc((size_t)8 * 1024 * 2048 * 4);
    bf16* hbuf = (bf16*)alloc((size_t)16384 * 2);                  // [2][2][8][512]
    unsigned int* flags = (unsigned int*)alloc(32 * 4);

    cvt_xpad_kernel<<<(8 * 2002 * 128 + 255) / 256, 256, 0, stream>>>(x, xpad);
    transpose_cvt_kernel<bf16><<<dim3(128, 12), 256, 0, stream>>>(w1, W1T, 384, 4096, 384);
    transpose_cvt_kernel<bf16><<<dim3(32, 384), 256, 0, stream>>>(w2, W2T, 12288, 1024, 12288);
    transpose_cvt_kernel<bf16><<<dim3(64, 32), 256, 0, stream>>>(wk, WkT, 1000, 2048, 1024);
    transpose_split_kernel<<<dim3(64, 16), 256, 0, stream>>>(wr, WrHi, WrLo, 512, 2048);
    zero_aux_kernel<<<(8 * 4096 + 16416 + 255) / 256, 256, 0, stream>>>(h1, hbuf, flags);

    gemm_kernel<0><<<dim3(32, 125), 256, 0, stream>>>(xpad, W1T, b1, (void*)h1);
    gemm_kernel<1><<<dim3(8, 63), 256, 0, stream>>>(h1, W2T, b2, (void*)h2T);
    gemm_kernel<2><<<dim3(16, 64), 256, 0, stream>>>(h2T, WkT, lb, (void*)Zin);

    lstm_persist_kernel<<<32, 256, 0, stream>>>(Zin, WrHi, WrLo, hbuf, flags, out);
}

// Round 2
// 5087.043 us; speedup vs baseline: 2.4926x; 1.3093x over previous
//
#include <hip/hip_runtime.h>
#include <cmath>
#include <cstdint>

typedef __bf16 bf16;
typedef __bf16 bf16x8 __attribute__((ext_vector_type(8)));
typedef float f32x4 __attribute__((ext_vector_type(4)));

static __device__ __forceinline__ float gelu_exact(float x) {
    return 0.5f * x * (1.f + erff(x * 0.70710678118654752f));
}

// ---------- fp32 -> bf16 convert of x with SAME padding rows (t=-1 and t=2000 zeroed) ----------
__global__ void cvt_xpad_kernel(const float* __restrict__ x, bf16* __restrict__ xp) {
    int idx = blockIdx.x * 256 + threadIdx.x;
    if (idx >= 8 * 2002 * 128) return;
    int c = idx & 127;
    int rest = idx >> 7;            // b*2002 + tp
    int tp = rest % 2002;
    int b = rest / 2002;
    float v = 0.f;
    if (tp >= 1 && tp <= 2000) v = x[(b * 2000 + tp - 1) * 128 + c];
    xp[idx] = (bf16)v;
}

// ---------- generic transpose+convert: in fp32 [R][C] -> out [C][Rpad], zero pad r in [R,Rpad) ----------
template <typename OT>
__global__ void transpose_cvt_kernel(const float* __restrict__ in, OT* __restrict__ out,
                                     int R, int C, int Rpad) {
    __shared__ float tile[32][33];
    int tx = threadIdx.x & 31, ty = threadIdx.x >> 5;   // 32 x 8
    int r0 = blockIdx.y * 32, c0 = blockIdx.x * 32;
    for (int i = ty; i < 32; i += 8) {
        int r = r0 + i, c = c0 + tx;
        tile[i][tx] = (r < R && c < C) ? in[(size_t)r * C + c] : 0.f;
    }
    __syncthreads();
    for (int i = ty; i < 32; i += 8) {
        int c = c0 + i, r = r0 + tx;
        if (c < C && r < Rpad) out[(size_t)c * Rpad + r] = (OT)tile[tx][i];
    }
}

// ---------- transpose + split fp32 -> (hi, lo) bf16 pair: in [R][C] -> out [C][R] ----------
__global__ void transpose_split_kernel(const float* __restrict__ in, bf16* __restrict__ hi,
                                       bf16* __restrict__ lo, int R, int C) {
    __shared__ float tile[32][33];
    int tx = threadIdx.x & 31, ty = threadIdx.x >> 5;
    int r0 = blockIdx.y * 32, c0 = blockIdx.x * 32;
    for (int i = ty; i < 32; i += 8) {
        int r = r0 + i, c = c0 + tx;
        tile[i][tx] = (r < R && c < C) ? in[(size_t)r * C + c] : 0.f;
    }
    __syncthreads();
    for (int i = ty; i < 32; i += 8) {
        int c = c0 + i, r = r0 + tx;
        if (c < C && r < R) {
            float v = tile[tx][i];
            bf16 h = (bf16)v;
            size_t o = (size_t)c * R + r;
            hi[o] = h;
            lo[o] = (bf16)(v - (float)h);
        }
    }
}

// ---------- zero h1 pad row (t=2000 per batch) + persistent-LSTM state (hbuf32, flags) ----------
__global__ void zero_aux_kernel(bf16* __restrict__ h1, float* __restrict__ hbuf32,
                                unsigned int* __restrict__ flags) {
    int idx = blockIdx.x * 256 + threadIdx.x;
    if (idx < 8 * 4096) {
        int b = idx >> 12, n = idx & 4095;
        h1[((size_t)(b * 2001 + 2000)) * 4096 + n] = (bf16)0.f;
    }
    int k = idx - 8 * 4096;
    if (k >= 0 && k < 8192) hbuf32[k] = 0.f;            // [2 par][8][512] fp32
    if (k >= 8192 && k < 8224) flags[k - 8192] = 0u;    // 32 flags
}

// ---------- unified bf16 MFMA GEMM, 128x128 tile, BK=32, 256 thr (4 waves, each 64x64) ----------
// MODE 0: conv1  M=16000(b,t)    K=384  (tap,cin)  N=4096  A=xpad[b][t+tap][c]      out: gelu -> h1 bf16 [b][t][n]
// MODE 1: conv2  M=8000 (b,t')   K=12288(tap,cin)  N=1024  A=h1[b][2t'+tap][c]      out: gelu -> h2T bf16 [b][n][t']
// MODE 2: zin    M=8192 (b,s)    K=1024 (f,pad)    N=2048  A=h2T[b][s][f]           out: +bias -> Zin fp32 [b][s][n]
template <int MODE>
__launch_bounds__(256)
__global__ void gemm_kernel(const bf16* __restrict__ A, const bf16* __restrict__ BT,
                            const float* __restrict__ bias, void* __restrict__ Cout) {
    constexpr int KTOT = (MODE == 0) ? 384 : (MODE == 1) ? 12288 : 1024;
    constexpr int MTOT = (MODE == 0) ? 16000 : (MODE == 1) ? 8000 : 8192;
    __shared__ __align__(16) bf16 As[128 * 32];
    __shared__ __align__(16) bf16 Bs[128 * 32];
    const int tid = threadIdx.x;
    const int lane = tid & 63, wave = tid >> 6;
    const int m0 = blockIdx.y * 128, n0 = blockIdx.x * 128;
    const int wm = (wave >> 1) * 64, wn = (wave & 1) * 64;

    f32x4 acc[4][4];
#pragma unroll
    for (int mi = 0; mi < 4; ++mi)
#pragma unroll
        for (int ni = 0; ni < 4; ++ni) acc[mi][ni] = (f32x4){0.f, 0.f, 0.f, 0.f};

    for (int kt = 0; kt < KTOT / 32; ++kt) {
        const int k0 = kt * 32;
        __syncthreads();
#pragma unroll
        for (int s = 0; s < 2; ++s) {
            int ch = tid + s * 256;          // 512 chunks of 16B = 8KB tile
            int row = ch >> 2;
            int ko = (ch & 3) * 8;
            int m = m0 + row;
            if (m > MTOT - 1) m = MTOT - 1;
            const bf16* ga;
            if (MODE == 0) {
                int b = m / 2000, t = m - b * 2000;
                ga = A + ((size_t)(b * 2002 + t + (k0 >> 7)) * 128 + (k0 & 127) + ko);
            } else if (MODE == 1) {
                int b = m / 1000, t = m - b * 1000;
                ga = A + ((size_t)(b * 2001 + 2 * t + (k0 >> 12)) * 4096 + (k0 & 4095) + ko);
            } else {
                ga = A + ((size_t)m * 1000 + k0 + ko);   // overruns row end by <=24 elems; B rows are zero there
            }
            *(uint4*)&As[ch * 8] = *(const uint4*)ga;
            const bf16* gb = BT + ((size_t)(n0 + row) * KTOT + k0 + ko);
            *(uint4*)&Bs[ch * 8] = *(const uint4*)gb;
        }
        __syncthreads();
        bf16x8 af[4], bfr[4];
#pragma unroll
        for (int i = 0; i < 4; ++i)
            af[i] = *(const bf16x8*)&As[(wm + i * 16 + (lane & 15)) * 32 + (lane >> 4) * 8];
#pragma unroll
        for (int i = 0; i < 4; ++i)
            bfr[i] = *(const bf16x8*)&Bs[(wn + i * 16 + (lane & 15)) * 32 + (lane >> 4) * 8];
#pragma unroll
        for (int mi = 0; mi < 4; ++mi)
#pragma unroll
            for (int ni = 0; ni < 4; ++ni)
                acc[mi][ni] = __builtin_amdgcn_mfma_f32_16x16x32_bf16(af[mi], bfr[ni], acc[mi][ni], 0, 0, 0);
    }

#pragma unroll
    for (int mi = 0; mi < 4; ++mi) {
        int rb = m0 + wm + mi * 16 + (lane >> 4) * 4;
#pragma unroll
        for (int ni = 0; ni < 4; ++ni) {
            int col = n0 + wn + ni * 16 + (lane & 15);
#pragma unroll
            for (int i = 0; i < 4; ++i) {
                int row = rb + i;
                float v = acc[mi][ni][i];
                if (MODE == 0) {
                    float y = gelu_exact(v + bias[col]);
                    int b = row / 2000, t = row - b * 2000;
                    ((bf16*)Cout)[(size_t)(b * 2001 + t) * 4096 + col] = (bf16)y;
                } else if (MODE == 1) {
                    if (row < 8000) {
                        float y = gelu_exact(v + bias[col]);
                        int b = row / 1000, t = row - b * 1000;
                        ((bf16*)Cout)[(size_t)(b * 1024 + col) * 1000 + t] = (bf16)y;
                    }
                } else {
                    ((float*)Cout)[(size_t)row * 2048 + col] = v + bias[col];
                }
            }
        }
    }
}

// ---------- persistent LSTM: all 1024 steps in ONE kernel, 32 wgs, fence-free L3 exchange ----------
// wg w owns hidden units [16w, 16w+16). Wr slice (64 gate-cols x 512, split hi/lo bf16) lives in LDS
// for the whole sequence. h is exchanged as fp32 through L3 via agent-scope atomics (no cache
// maintenance fences). hi/lo bf16 split is recomputed from fp32 at staging => bit-identical math.
__launch_bounds__(256)
__global__ void lstm_persist_kernel(const float* __restrict__ Zin,
                                    const bf16* __restrict__ WrHi,
                                    const bf16* __restrict__ WrLo,
                                    float* __restrict__ hbuf32,
                                    unsigned int* __restrict__ flags,
                                    float* __restrict__ out) {
    __shared__ __align__(16) unsigned char WrS[2][65536];  // [plane][64 cols x 512 k] bf16, XOR-swizzled
    __shared__ __align__(16) unsigned char hS[2][8192];    // [plane][8 rows x 512 k] bf16, XOR-swizzled
    __shared__ float zex[4][128];                          // [gate][b*16+u]
    const int tid = threadIdx.x;
    const int wv = tid >> 6;          // wave == gate
    const int w = blockIdx.x;

    // one-time: load Wr slice (both planes) into LDS with ((col&7)<<4) byte-XOR swizzle
    for (int idx = tid; idx < 8192; idx += 256) {
        int p = idx >> 12, r = idx & 4095;
        int lc = r >> 6, co = r & 63;
        int gcol = (lc >> 4) * 512 + w * 16 + (lc & 15);
        const bf16* src = (p ? WrLo : WrHi) + (size_t)gcol * 512 + co * 8;
        unsigned dst = (unsigned)(lc * 1024 + ((co * 16) ^ ((lc & 7) << 4)));
        *(uint4*)&WrS[p][dst] = *(const uint4*)src;
    }

    const int b = tid >> 4, u = tid & 15, j = w * 16 + u;  // epilogue mapping (tid<128)
    float c_state = 0.f;
    float zin0 = 0.f, zin1 = 0.f, zin2 = 0.f, zin3 = 0.f;
    const float invf = powf(10000.f, -(float)(2 * (j >> 1)) * (1.f / 512.f));
    if (tid < 128) {
        const float* zp = Zin + (size_t)(b * 1024) * 2048;
        zin0 = zp[j]; zin1 = zp[512 + j]; zin2 = zp[1024 + j]; zin3 = zp[1536 + j];
    }

    const int lane = tid & 63;
    const int rowsel = lane & 15;       // A row (batch), rows 8..15 duplicate rows 0..7 (ignored)
    const int kq = lane >> 4;           // k quarter
    const int lc = wv * 16 + rowsel;    // local B col
    const unsigned aswz = (unsigned)((rowsel & 7) << 4);
    const unsigned bswz = (unsigned)((lc & 7) << 4);
    const unsigned abase = (unsigned)((rowsel & 7) * 1024);
    const unsigned bbase = (unsigned)(lc * 1024);

    // staging indices: thread -> 16 consecutive k of one batch row
    const int srow = tid >> 5;
    const unsigned sco = (unsigned)((tid & 31) * 2);
    const unsigned ssw = (unsigned)((srow & 7) << 4);
    const unsigned sbase = (unsigned)(srow * 1024);

    for (int t = 0; t < 1024; ++t) {
        const int par = t & 1;
        // stage h_{t-1}: agent atomic loads from L3 (coherent, no fence), split to hi/lo, swizzle
        {
            float* hb = hbuf32 + par * 4096;
            float v[16];
#pragma unroll
            for (int i = 0; i < 16; ++i)
                v[i] = __hip_atomic_load(&hb[srow * 512 + sco * 8 + i], __ATOMIC_RELAXED,
                                         __HIP_MEMORY_SCOPE_AGENT);
            bf16x8 hi0, hi1, lo0, lo1;
#pragma unroll
            for (int i = 0; i < 8; ++i) {
                bf16 h0 = (bf16)v[i];
                hi0[i] = h0; lo0[i] = (bf16)(v[i] - (float)h0);
                bf16 h1 = (bf16)v[8 + i];
                hi1[i] = h1; lo1[i] = (bf16)(v[8 + i] - (float)h1);
            }
            *(bf16x8*)&hS[0][sbase + ((sco * 16) ^ ssw)] = hi0;
            *(bf16x8*)&hS[0][sbase + (((sco + 1) * 16) ^ ssw)] = hi1;
            *(bf16x8*)&hS[1][sbase + ((sco * 16) ^ ssw)] = lo0;
            *(bf16x8*)&hS[1][sbase + (((sco + 1) * 16) ^ ssw)] = lo1;
        }
        __syncthreads();   // S1: hS ready
        // z-tile for gate wv: 16 k-steps x 3 products (hh, lh, hl), 3 independent acc chains
        f32x4 acc0 = {0.f, 0.f, 0.f, 0.f}, acc1 = {0.f, 0.f, 0.f, 0.f}, acc2 = {0.f, 0.f, 0.f, 0.f};
#pragma unroll
        for (int kk = 0; kk < 16; ++kk) {
            unsigned ko = (unsigned)((kk * 4 + kq) * 16);
            bf16x8 ah = *(const bf16x8*)&hS[0][abase + (ko ^ aswz)];
            bf16x8 al = *(const bf16x8*)&hS[1][abase + (ko ^ aswz)];
            bf16x8 bh = *(const bf16x8*)&WrS[0][bbase + (ko ^ bswz)];
            bf16x8 bl = *(const bf16x8*)&WrS[1][bbase + (ko ^ bswz)];
            acc0 = __builtin_amdgcn_mfma_f32_16x16x32_bf16(ah, bh, acc0, 0, 0, 0);
            acc1 = __builtin_amdgcn_mfma_f32_16x16x32_bf16(al, bh, acc1, 0, 0, 0);
            acc2 = __builtin_amdgcn_mfma_f32_16x16x32_bf16(ah, bl, acc2, 0, 0, 0);
        }
        if (kq < 2) {   // valid batch rows 0..7
#pragma unroll
            for (int i = 0; i < 4; ++i)
                zex[wv][(kq * 4 + i) * 16 + rowsel] = acc0[i] + acc1[i] + acc2[i];
        }
        __syncthreads();   // S2: zex ready
        float hval = 0.f;
        if (tid < 128) {
            float zi = zex[0][tid] + zin0;
            float zf = zex[1][tid] + zin1;
            float zg = zex[2][tid] + zin2;
            float zo = zex[3][tid] + zin3;
            float ig = 1.f / (1.f + expf(-zi));
            float fg = 1.f / (1.f + expf(-zf));
            float og = 1.f / (1.f + expf(-zo));
            float c = fg * c_state + ig * tanhf(zg);
            c_state = c;
            hval = og * tanhf(c);
            // coherent store straight to L3 (atomic RMW, no fence needed)
            (void)__hip_atomic_exchange(&hbuf32[(par ^ 1) * 4096 + b * 512 + j], hval,
                                        __ATOMIC_RELAXED, __HIP_MEMORY_SCOPE_AGENT);
        }
        __syncthreads();   // S3: per-thread vmcnt drain => all h exchanges completed at L3
        if (t < 1023 && tid == 0)
            (void)__hip_atomic_exchange(&flags[w], (unsigned)(t + 1),
                                        __ATOMIC_RELAXED, __HIP_MEMORY_SCOPE_AGENT);
        // off-critical-path work overlaps other wgs' spin
        if (tid < 128) {
            float ang = (float)t * invf;
            float pe = (j & 1) ? cosf(ang) : sinf(ang);
            out[(size_t)(b * 1024 + t) * 512 + j] = hval + pe;
            if (t < 1023) {
                const float* zp = Zin + (size_t)(b * 1024 + t + 1) * 2048;
                zin0 = zp[j]; zin1 = zp[512 + j]; zin2 = zp[1024 + j]; zin3 = zp[1536 + j];
            }
        }
        if (t < 1023) {
            if (tid < 64) {            // wave 0 polls; other waves park at S4
                const unsigned tgt = (unsigned)(t + 1);
                for (;;) {
                    unsigned f = __hip_atomic_load(&flags[lane & 31], __ATOMIC_RELAXED,
                                                   __HIP_MEMORY_SCOPE_AGENT);
                    if (__all((int)(f >= tgt))) break;
                    __builtin_amdgcn_s_sleep(1);
                }
            }
            __builtin_amdgcn_fence(__ATOMIC_ACQUIRE, "workgroup");   // compile-time + cheap HW order
            __syncthreads();   // S4: release all waves into next step
        }
    }
}

extern "C" void kernel_launch(void* const* d_in, const int* in_sizes, int n_in,
                              void* d_out, int out_size, void* d_ws, size_t ws_size,
                              hipStream_t stream) {
    const float* x  = (const float*)d_in[0];
    const float* w1 = (const float*)d_in[1];
    const float* b1 = (const float*)d_in[2];
    const float* w2 = (const float*)d_in[3];
    const float* b2 = (const float*)d_in[4];
    const float* wk = (const float*)d_in[5];
    const float* wr = (const float*)d_in[6];
    const float* lb = (const float*)d_in[7];
    float* out = (float*)d_out;

    uint8_t* ws = (uint8_t*)d_ws;
    size_t off = 0;
    auto alloc = [&](size_t bytes) {
        void* p = ws + off;
        off += (bytes + 255) & ~(size_t)255;
        return p;
    };
    bf16* xpad = (bf16*)alloc((size_t)8 * 2002 * 128 * 2);
    bf16* W1T  = (bf16*)alloc((size_t)4096 * 384 * 2);
    bf16* W2T  = (bf16*)alloc((size_t)1024 * 12288 * 2);
    bf16* WkT  = (bf16*)alloc((size_t)2048 * 1024 * 2);
    bf16* WrHi = (bf16*)alloc((size_t)2048 * 512 * 2);
    bf16* WrLo = (bf16*)alloc((size_t)2048 * 512 * 2);
    bf16* h1   = (bf16*)alloc((size_t)8 * 2001 * 4096 * 2);
    bf16* h2T  = (bf16*)alloc((size_t)8 * 1024 * 1000 * 2 + 256);  // +slack for k-tail overread
    float* Zin = (float*)alloc((size_t)8 * 1024 * 2048 * 4);
    float* hbuf32 = (float*)alloc((size_t)8192 * 4);               // [2 par][8][512] fp32
    unsigned int* flags = (unsigned int*)alloc(32 * 4);

    cvt_xpad_kernel<<<(8 * 2002 * 128 + 255) / 256, 256, 0, stream>>>(x, xpad);
    transpose_cvt_kernel<bf16><<<dim3(128, 12), 256, 0, stream>>>(w1, W1T, 384, 4096, 384);
    transpose_cvt_kernel<bf16><<<dim3(32, 384), 256, 0, stream>>>(w2, W2T, 12288, 1024, 12288);
    transpose_cvt_kernel<bf16><<<dim3(64, 32), 256, 0, stream>>>(wk, WkT, 1000, 2048, 1024);
    transpose_split_kernel<<<dim3(64, 16), 256, 0, stream>>>(wr, WrHi, WrLo, 512, 2048);
    zero_aux_kernel<<<(8 * 4096 + 8224 + 255) / 256, 256, 0, stream>>>(h1, hbuf32, flags);

    gemm_kernel<0><<<dim3(32, 125), 256, 0, stream>>>(xpad, W1T, b1, (void*)h1);
    gemm_kernel<1><<<dim3(8, 63), 256, 0, stream>>>(h1, W2T, b2, (void*)h2T);
    gemm_kernel<2><<<dim3(16, 64), 256, 0, stream>>>(h2T, WkT, lb, (void*)Zin);

    lstm_persist_kernel<<<32, 256, 0, stream>>>(Zin, WrHi, WrLo, hbuf32, flags, out);
}